// Round 1
// baseline (258.396 us; speedup 1.0000x reference)
//
#include <hip/hip_runtime.h>

#define BN 4
#define EN 32
#define NPIX (512 * 512)   // 262144 = 2^18
#define CSEG 2048
#define NEDGE 8192

#define DELTA_VAR 0.1f
#define DELTA_DIST 0.3f

// ---- accumulate kernel geometry ----
#define ECHUNK 8
#define NECH (EN / ECHUNK)            // 4
#define PIXBLK 32                     // pixel-blocks per (b, echunk)
#define PIX_PER_BLK (NPIX / PIXBLK)   // 8192
#define ATHREADS 512

// ws layout (floats):
//   counts : [BN][CSEG]           offset 0          (8192)
//   sums   : [BN][EN][CSEG]       offset 8192       (262144)   <- flush-coalesced layout
//   means  : [BN][CSEG][EN]       offset 270336     (262144)   <- gather-friendly layout
#define WS_COUNTS 0
#define WS_SUMS (BN * CSEG)
#define WS_MEANS (WS_SUMS + BN * EN * CSEG)
#define WS_TOTAL (WS_MEANS + BN * CSEG * EN)

// -------- kernel 1: LDS-aggregated segment sums + counts --------
__global__ __launch_bounds__(ATHREADS) void rag_accum(
    const float* __restrict__ emb, const int* __restrict__ seg,
    float* __restrict__ counts, float* __restrict__ sums) {
  __shared__ float lsum[ECHUNK * CSEG];  // 64 KB, [e][c] so random c spreads banks
  __shared__ float lcnt[CSEG];           // 8 KB (used by ech==0 blocks only)

  const int blk = blockIdx.x;  // grid = BN * NECH * PIXBLK = 512
  const int pb = blk % PIXBLK;
  const int ech = (blk / PIXBLK) % NECH;
  const int b = blk / (PIXBLK * NECH);

  for (int i = threadIdx.x; i < ECHUNK * CSEG; i += ATHREADS) lsum[i] = 0.0f;
  if (ech == 0)
    for (int i = threadIdx.x; i < CSEG; i += ATHREADS) lcnt[i] = 0.0f;
  __syncthreads();

  const int p0 = pb * PIX_PER_BLK;
  const float* __restrict__ eb = emb + ((size_t)b * EN + (size_t)ech * ECHUNK) * NPIX;
  const int* __restrict__ sb = seg + (size_t)b * NPIX;

  for (int p = p0 + threadIdx.x; p < p0 + PIX_PER_BLK; p += ATHREADS) {
    const int s = sb[p];
    if (ech == 0) atomicAdd(&lcnt[s], 1.0f);
#pragma unroll
    for (int e = 0; e < ECHUNK; e++) {
      atomicAdd(&lsum[e * CSEG + s], eb[(size_t)e * NPIX + p]);
    }
  }
  __syncthreads();

  // flush: lanes hit consecutive c -> coalesced atomic runs
  float* __restrict__ gs = sums + (size_t)b * EN * CSEG;
  for (int i = threadIdx.x; i < ECHUNK * CSEG; i += ATHREADS) {
    const float v = lsum[i];
    if (v != 0.0f) {
      const int e = i / CSEG;
      const int c = i - e * CSEG;
      atomicAdd(&gs[(size_t)(ech * ECHUNK + e) * CSEG + c], v);
    }
  }
  if (ech == 0) {
    float* __restrict__ gc = counts + (size_t)b * CSEG;
    for (int i = threadIdx.x; i < CSEG; i += ATHREADS) {
      const float v = lcnt[i];
      if (v != 0.0f) atomicAdd(&gc[i], v);
    }
  }
}

// -------- kernel 2: means = normalize(sums / max(count,1)); transpose to [B][C][E] --------
__global__ __launch_bounds__(256) void rag_finalize(
    const float* __restrict__ counts, const float* __restrict__ sums,
    float* __restrict__ means) {
  const int idx = blockIdx.x * 256 + threadIdx.x;
  if (idx >= BN * CSEG) return;
  const int b = idx / CSEG;
  const int c = idx - b * CSEG;
  const float inv = 1.0f / fmaxf(counts[idx], 1.0f);
  const float* __restrict__ sbase = sums + (size_t)b * EN * CSEG + c;
  float m[EN];
  float nrm = 0.0f;
#pragma unroll
  for (int e = 0; e < EN; e++) {
    const float v = sbase[(size_t)e * CSEG] * inv;  // lane-consecutive c -> coalesced
    m[e] = v;
    nrm += v * v;
  }
  const float s = 1.0f / fmaxf(sqrtf(nrm), 1e-10f);
  float* __restrict__ mb = means + (size_t)idx * EN;
#pragma unroll
  for (int e = 0; e < EN; e++) mb[e] = m[e] * s;
}

// -------- kernel 3: intra loss (second streaming pass over embeddings) --------
#define ITHREADS 256
__global__ __launch_bounds__(ITHREADS) void rag_intra(
    const float* __restrict__ emb, const int* __restrict__ seg,
    const float* __restrict__ counts, const float* __restrict__ means,
    float* __restrict__ out) {
  float acc = 0.0f;
  const int total = BN * NPIX;
  for (int i = blockIdx.x * ITHREADS + threadIdx.x; i < total;
       i += gridDim.x * ITHREADS) {
    const int b = i >> 18;          // NPIX = 2^18
    const int p = i & (NPIX - 1);
    const int s = seg[i];
    const float4* __restrict__ mv =
        (const float4*)(means + ((size_t)b * CSEG + s) * EN);
    const float* __restrict__ eb = emb + (size_t)b * EN * NPIX + p;
    float dot = 0.0f;
#pragma unroll
    for (int e4 = 0; e4 < EN / 4; e4++) {
      const float4 m4 = mv[e4];
      dot += m4.x * eb[(size_t)(e4 * 4 + 0) * NPIX];
      dot += m4.y * eb[(size_t)(e4 * 4 + 1) * NPIX];
      dot += m4.z * eb[(size_t)(e4 * 4 + 2) * NPIX];
      dot += m4.w * eb[(size_t)(e4 * 4 + 3) * NPIX];
    }
    const float d = 1.0f - dot - DELTA_VAR;  // max(d - delta_var, 0)
    if (d > 0.0f) acc += d / counts[b * CSEG + s];
  }
  // block reduction
  for (int o = 32; o > 0; o >>= 1) acc += __shfl_down(acc, o, 64);
  __shared__ float wsum[ITHREADS / 64];
  const int lane = threadIdx.x & 63;
  const int wid = threadIdx.x >> 6;
  if (lane == 0) wsum[wid] = acc;
  __syncthreads();
  if (threadIdx.x == 0) {
    float bsum = 0.0f;
#pragma unroll
    for (int w = 0; w < ITHREADS / 64; w++) bsum += wsum[w];
    atomicAdd(out, bsum * (1.0f / CSEG));  // BETA = 1
  }
}

// -------- kernel 4: inter loss over RAG edges --------
#define JTHREADS 256
__global__ __launch_bounds__(JTHREADS) void rag_inter(
    const int* __restrict__ edges, const float* __restrict__ weights,
    const float* __restrict__ means, float* __restrict__ out) {
  const int idx = blockIdx.x * JTHREADS + threadIdx.x;
  float val = 0.0f;
  if (idx < BN * NEDGE) {
    const int b = idx >> 13;  // NEDGE = 2^13
    const int k = idx & (NEDGE - 1);
    const int e0 = edges[(size_t)b * 2 * NEDGE + k];
    const int e1 = edges[(size_t)b * 2 * NEDGE + NEDGE + k];
    const float w = weights[idx];
    const float4* __restrict__ m0 =
        (const float4*)(means + ((size_t)b * CSEG + e0) * EN);
    const float4* __restrict__ m1 =
        (const float4*)(means + ((size_t)b * CSEG + e1) * EN);
    float dot = 0.0f;
#pragma unroll
    for (int e4 = 0; e4 < EN / 4; e4++) {
      const float4 a = m0[e4];
      const float4 c = m1[e4];
      dot += a.x * c.x + a.y * c.y + a.z * c.z + a.w * c.w;
    }
    val = fmaxf(DELTA_DIST - (1.0f - dot) * w, 0.0f);
  }
  for (int o = 32; o > 0; o >>= 1) val += __shfl_down(val, o, 64);
  __shared__ float wsum[JTHREADS / 64];
  const int lane = threadIdx.x & 63;
  const int wid = threadIdx.x >> 6;
  if (lane == 0) wsum[wid] = val;
  __syncthreads();
  if (threadIdx.x == 0) {
    float bsum = 0.0f;
#pragma unroll
    for (int w = 0; w < JTHREADS / 64; w++) bsum += wsum[w];
    atomicAdd(out, bsum * (1.0f / NEDGE));  // ALPHA = 1
  }
}

extern "C" void kernel_launch(void* const* d_in, const int* in_sizes, int n_in,
                              void* d_out, int out_size, void* d_ws, size_t ws_size,
                              hipStream_t stream) {
  const float* emb = (const float*)d_in[0];     // [B][E][H][W]
  const int* seg = (const int*)d_in[1];         // [B][1][H][W]
  const int* edges = (const int*)d_in[2];       // [B][2][NEDGE]
  const float* weights = (const float*)d_in[3]; // [B][NEDGE]
  float* out = (float*)d_out;

  float* ws = (float*)d_ws;
  float* counts = ws + WS_COUNTS;
  float* sums = ws + WS_SUMS;
  float* means = ws + WS_MEANS;

  // zero the atomic accumulators (counts + sums) and the scalar output
  hipMemsetAsync(d_ws, 0, (size_t)WS_MEANS * sizeof(float), stream);
  hipMemsetAsync(d_out, 0, sizeof(float), stream);

  rag_accum<<<BN * NECH * PIXBLK, ATHREADS, 0, stream>>>(emb, seg, counts, sums);
  rag_finalize<<<(BN * CSEG + 255) / 256, 256, 0, stream>>>(counts, sums, means);
  rag_intra<<<1024, ITHREADS, 0, stream>>>(emb, seg, counts, means, out);
  rag_inter<<<(BN * NEDGE + JTHREADS - 1) / JTHREADS, JTHREADS, 0, stream>>>(
      edges, weights, means, out);
}